// Round 2
// baseline (150.523 us; speedup 1.0000x reference)
//
#include <hip/hip_runtime.h>
#include <hip/hip_bf16.h>

typedef __bf16 bf16x8 __attribute__((ext_vector_type(8)));
typedef float f32x4 __attribute__((ext_vector_type(4)));

#define NUM_TEAMS 100000
#define NUM_MATCHES 1000000
#define LOG2E 1.4426950408889634f
#define NTILES 1563         // ceil(100000/64)
#define GRID 256            // persistent: 1 block/CU (LDS 134KB), ~6.1 tiles/block

__device__ __forceinline__ unsigned short f2bf(float x) {
    __hip_bfloat16 h = __float2bfloat16(x);
    return reinterpret_cast<unsigned short&>(h);
}
// single-instruction packed f32x2 -> bf16x2. No builtin on gfx950 (m240) -> asm.
__device__ __forceinline__ unsigned int cvtpk(float a, float b) {
    unsigned int r;
    asm("v_cvt_pk_bf16_f32 %0, %1, %2" : "=v"(r) : "v"(a), "v"(b));
    return r;
}
__device__ __forceinline__ float exp2_(float x) {
    float r; asm("v_exp_f32 %0, %1" : "=v"(r) : "v"(x)); return r;
}
__device__ __forceinline__ float rcp_(float x) {
    float r; asm("v_rcp_f32 %0, %1" : "=v"(r) : "v"(x)); return r;
}
// async global->LDS, 16B per lane. Dest = wave-uniform base + lane*16 (m104/m108).
__device__ __forceinline__ void load_lds16(const float* g, float* l) {
    __builtin_amdgcn_global_load_lds(
        (const __attribute__((address_space(1))) void*)g,
        (__attribute__((address_space(3))) void*)l, 16, 0, 0);
}
// barrier that drains ONLY lgkm (LDS) — keeps next-tile global_load_lds staging
// in flight across act/proj phases. sched_barrier(0) both sides per rule #18.
__device__ __forceinline__ void barrier_lgkm() {
    asm volatile("s_waitcnt lgkmcnt(0)" ::: "memory");
    __builtin_amdgcn_sched_barrier(0);
    __builtin_amdgcn_s_barrier();
    __builtin_amdgcn_sched_barrier(0);
}

// ---------------- prep: pack W fragment-major bf16; biases pre-scaled by log2e ----------------
// Wpk u16 index = G*16384 + gate*4096 + ks*512 + l4*128 + l15*8 + e
//   holds W[row = gate*128 + G*16 + l15][k = ks*32 + l4*8 + e]  (W = [W_ih | W_hh])
__global__ __launch_bounds__(256) void prep_kernel(
    const float* __restrict__ W_ih, const float* __restrict__ W_hh,
    const float* __restrict__ b_ih, const float* __restrict__ b_hh,
    unsigned short* __restrict__ Wpk, float* __restrict__ biasc)
{
    int gid = blockIdx.x * 256 + threadIdx.x;   // 131072 bf16 elements
    int e = gid & 7;
    int chunk = gid >> 3;                        // 16B chunk id
    int l15 = chunk & 15;
    int l4 = (chunk >> 4) & 3;
    int rest = chunk >> 6;
    int ks = rest & 7;
    int gate = (rest >> 3) & 3;
    int G = rest >> 5;
    int row = gate * 128 + G * 16 + l15;
    int k = ks * 32 + l4 * 8 + e;
    float v = (k < 128) ? W_ih[row * 128 + k] : W_hh[row * 128 + (k - 128)];
    Wpk[gid] = f2bf(v);
    if (gid < 512) {
        float b = b_ih[gid] + b_hh[gid];
        float scale = ((gid >> 7) == 2) ? (2.0f * LOG2E) : (-LOG2E);
        biasc[gid] = b * scale;
    }
}

// ---------------- persistent LSTM + fused proj ----------------
// 256 blocks x 512 thr (8 waves), each loops over ~6 tiles of 64 teams x 128 hcols.
// B fragments (128 VGPR/wave) + W_out LDS + biases loaded ONCE per block — the
// K-loop has zero global loads and B L2 traffic drops 6x. A(t+1) staged f32 via
// global_load_lds into the idle half of a 2x64KB LDS dbuf, issued at tile start;
// mid-tile barriers drain lgkm only so staging stays in flight until tile end.
// Regs: 128 Bf + 64 acc(AGPR) + ~40 temps @ 2 waves/SIMD budget (512) — no spill.
__global__ __launch_bounds__(512, 2) void lstm_kernel(
    const float* __restrict__ inputs, const float* __restrict__ hx,
    const float* __restrict__ cx, const unsigned short* __restrict__ Wpk,
    const float* __restrict__ biasc, const float* __restrict__ W_out,
    float* __restrict__ projP)
{
    __shared__ __align__(16) float Af[2][64 * 256];  // 2 x 64 KB f32 A tiles (dbuf)
    __shared__ float Wlds[768];
    const int tid = threadIdx.x;
    const int lane = tid & 63;
    const int w = tid >> 6;                          // wave 0..7
    const int l15 = lane & 15, l4 = lane >> 4;
    const int hcol = w * 16 + l15;                   // global 0..127

    // ---- once-per-block setup ----
    // B fragments resident in VGPRs: wave w holds G-group w (4 gates x 8 ks)
    const unsigned short* bpg = Wpk + (size_t)w * 16384 + lane * 8;
    bf16x8 Bf[4][8];
    #pragma unroll
    for (int g = 0; g < 4; ++g)
        #pragma unroll
        for (int ks = 0; ks < 8; ++ks)
            Bf[g][ks] = *(const bf16x8*)(bpg + g * 4096 + ks * 512);

    const float bic = biasc[hcol];                   // -c*bi
    const float bfc = biasc[128 + hcol];             // -c*bf
    const float bgc = biasc[256 + hcol];             // +2c*bg
    const float boc = biasc[384 + hcol];             // -c*bo

    Wlds[tid] = W_out[tid];
    if (tid < 256) Wlds[512 + tid] = W_out[512 + tid];

    // staging geometry: wave w stages rows p*8+w; LDS unit `lane` holds source
    // unit lane^(row&7) (involution swizzle on low 3 bits; row&7 == w)
    const int su = lane ^ w;
    const int scol = su * 4;
    const float* sbase = (scol < 128) ? inputs + scol : hx + (scol - 128);
    // A-frag read offsets: unit s = ks*8 + l4*2 (+1); low3(s) ^ (row&7), row&7 = l15&7
    const int u0 = ((l4 * 2) ^ (l15 & 7)) << 4;
    const int u1 = ((l4 * 2 + 1) ^ (l15 & 7)) << 4;

    const int t0 = blockIdx.x;
    // prologue: stage first tile
    {
        float* buf = &Af[0][0];
        #pragma unroll
        for (int p = 0; p < 8; ++p) {
            int row = p * 8 + w;
            int team = t0 * 64 + row; if (team >= NUM_TEAMS) team = NUM_TEAMS - 1;
            load_lds16(sbase + (size_t)team * 128, buf + row * 256 + lane * 4);
        }
    }
    __syncthreads();                                 // drain staging + Wlds

    int cur = 0;
    for (int t = t0; t < NTILES; t += GRID, cur ^= 1) {
        const int brow = t * 64;

        // issue staging of next tile into the idle buffer (fire-and-forget)
        if (t + GRID < NTILES) {
            float* buf = &Af[cur ^ 1][0];
            const int tb = (t + GRID) * 64;
            #pragma unroll
            for (int p = 0; p < 8; ++p) {
                int row = p * 8 + w;
                int team = tb + row; if (team >= NUM_TEAMS) team = NUM_TEAMS - 1;
                load_lds16(sbase + (size_t)team * 128, buf + row * 256 + lane * 4);
            }
        }
        // cx for this tile — in flight under the K-loop
        float cxa[16];
        #pragma unroll
        for (int m = 0; m < 4; ++m)
            #pragma unroll
            for (int j = 0; j < 4; ++j) {
                int team = brow + m * 16 + l4 * 4 + j;
                if (team >= NUM_TEAMS) team = NUM_TEAMS - 1;
                cxa[m * 4 + j] = cx[(size_t)team * 128 + hcol];
            }

        // ---- K-loop: pure LDS-read + cvtpk + MFMA (B in regs) ----
        f32x4 acc[4][4] = {};                        // [m][gate], 64 AGPRs
        const char* Ab = reinterpret_cast<const char*>(&Af[cur][0]);
        #pragma unroll
        for (int ks = 0; ks < 8; ++ks) {
            #pragma unroll
            for (int m = 0; m < 4; ++m) {
                const char* pa = Ab + (m * 16 + l15) * 1024 + ks * 128;
                f32x4 a0 = *reinterpret_cast<const f32x4*>(pa + u0);
                f32x4 a1 = *reinterpret_cast<const f32x4*>(pa + u1);
                union { uint4 q; bf16x8 v; } cc;
                cc.q.x = cvtpk(a0[0], a0[1]);
                cc.q.y = cvtpk(a0[2], a0[3]);
                cc.q.z = cvtpk(a1[0], a1[1]);
                cc.q.w = cvtpk(a1[2], a1[3]);
                bf16x8 af = cc.v;
                acc[m][0] = __builtin_amdgcn_mfma_f32_16x16x32_bf16(af, Bf[0][ks], acc[m][0], 0, 0, 0);
                acc[m][1] = __builtin_amdgcn_mfma_f32_16x16x32_bf16(af, Bf[1][ks], acc[m][1], 0, 0, 0);
                acc[m][2] = __builtin_amdgcn_mfma_f32_16x16x32_bf16(af, Bf[2][ks], acc[m][2], 0, 0, 0);
                acc[m][3] = __builtin_amdgcn_mfma_f32_16x16x32_bf16(af, Bf[3][ks], acc[m][3], 0, 0, 0);
            }
        }

        barrier_lgkm();                              // all A reads done; LDS[cur] becomes h

        // ---- activations; h -> swizzled f32 [64][128] over Af[cur] ----
        // C/D layout: col = l15 -> hcol, row = l4*4 + j -> team-local
        {
            char* lb = reinterpret_cast<char*>(&Af[cur][0]);
            #pragma unroll
            for (int m = 0; m < 4; ++m) {
                #pragma unroll
                for (int j = 0; j < 4; ++j) {
                    float si = rcp_(1.0f + exp2_(fmaf(acc[m][0][j], -LOG2E, bic)));
                    float sf = rcp_(1.0f + exp2_(fmaf(acc[m][1][j], -LOG2E, bfc)));
                    float tg = fmaf(-2.0f, rcp_(1.0f + exp2_(fmaf(acc[m][2][j], 2.0f * LOG2E, bgc))), 1.0f);
                    float so = rcp_(1.0f + exp2_(fmaf(acc[m][3][j], -LOG2E, boc)));
                    float cn = fmaf(sf, cxa[m * 4 + j], si * tg);
                    float tc = fmaf(-2.0f, rcp_(1.0f + exp2_(cn * (2.0f * LOG2E))), 1.0f);
                    float hn = so * tc;
                    int tl = m * 16 + l4 * 4 + j;
                    *reinterpret_cast<float*>(lb + ((tl * 512 + hcol * 4) ^ ((tl & 7) << 4))) = hn;
                }
            }
        }
        barrier_lgkm();                              // h visible

        // ---- fused proj: 8 threads/team, 16 hcols each, 6 final outputs ----
        {
            int tl = tid >> 3, sub = tid & 7;        // team-local 0..63, sub 0..7
            const char* lb = reinterpret_cast<const char*>(&Af[cur][0]);
            int hbase = tl * 512 + sub * 64;
            int hswz = (tl & 7) << 4;
            float a0 = 0.f, a1 = 0.f, a2 = 0.f, a3 = 0.f, a4 = 0.f, a5 = 0.f;
            #pragma unroll
            for (int c = 0; c < 4; ++c) {
                f32x4 h4 = *reinterpret_cast<const f32x4*>(lb + ((hbase + c * 16) ^ hswz));
                #pragma unroll
                for (int i = 0; i < 4; ++i) {
                    float h = h4[i];
                    int col = sub * 16 + c * 4 + i;  // global hcol 0..127
                    a0 += h * Wlds[col];       a1 += h * Wlds[256 + col]; a2 += h * Wlds[512 + col];
                    a3 += h * Wlds[128 + col]; a4 += h * Wlds[384 + col]; a5 += h * Wlds[640 + col];
                }
            }
            a0 += __shfl_xor(a0, 1); a1 += __shfl_xor(a1, 1); a2 += __shfl_xor(a2, 1);
            a3 += __shfl_xor(a3, 1); a4 += __shfl_xor(a4, 1); a5 += __shfl_xor(a5, 1);
            a0 += __shfl_xor(a0, 2); a1 += __shfl_xor(a1, 2); a2 += __shfl_xor(a2, 2);
            a3 += __shfl_xor(a3, 2); a4 += __shfl_xor(a4, 2); a5 += __shfl_xor(a5, 2);
            a0 += __shfl_xor(a0, 4); a1 += __shfl_xor(a1, 4); a2 += __shfl_xor(a2, 4);
            a3 += __shfl_xor(a3, 4); a4 += __shfl_xor(a4, 4); a5 += __shfl_xor(a5, 4);
            int team = brow + tl;
            if (sub == 0 && team < NUM_TEAMS) {
                float4* o = reinterpret_cast<float4*>(projP + (size_t)team * 8);
                o[0] = make_float4(a0, a1, a2, a2);  // home (full sum)
                o[1] = make_float4(a3, a4, a5, a5);  // away (full sum)
            }
        }
        __syncthreads();            // full drain: staging(t+1) complete, proj reads done
    }
}

// ---------------- match head: gather finals; logits + b_out ; softmax ----------------
__global__ __launch_bounds__(256) void match_kernel(
    const int* __restrict__ matches, const float* __restrict__ projP,
    const float* __restrict__ b_out, float* __restrict__ out)
{
    int m = blockIdx.x * 256 + threadIdx.x;
    if (m >= NUM_MATCHES) return;
    int2 mi = reinterpret_cast<const int2*>(matches)[m];
    const float4* pp = reinterpret_cast<const float4*>(projP);
    float4 hv = pp[(size_t)mi.x * 2 + 0];            // home
    float4 av = pp[(size_t)mi.y * 2 + 1];            // away
    float l0 = hv.x + av.x + b_out[0];
    float l1 = hv.y + av.y + b_out[1];
    float l2 = hv.z + av.z + b_out[2];
    float mx = fmaxf(l0, fmaxf(l1, l2));
    float e0 = __expf(l0 - mx), e1 = __expf(l1 - mx), e2 = __expf(l2 - mx);
    float inv = 1.0f / (e0 + e1 + e2);
    out[3 * m + 0] = e0 * inv;
    out[3 * m + 1] = e1 * inv;
    out[3 * m + 2] = e2 * inv;
}

extern "C" void kernel_launch(void* const* d_in, const int* in_sizes, int n_in,
                              void* d_out, int out_size, void* d_ws, size_t ws_size,
                              hipStream_t stream) {
    const float* inputs = (const float*)d_in[0];
    const float* hx     = (const float*)d_in[1];
    const float* cx     = (const float*)d_in[2];
    const int*   matches= (const int*)d_in[3];
    const float* W_ih   = (const float*)d_in[4];
    const float* W_hh   = (const float*)d_in[5];
    const float* b_ih   = (const float*)d_in[6];
    const float* b_hh   = (const float*)d_in[7];
    const float* W_out  = (const float*)d_in[8];
    const float* b_out  = (const float*)d_in[9];
    float* out = (float*)d_out;

    char* ws = (char*)d_ws;
    unsigned short* Wpk  = (unsigned short*)ws;                  // 256 KB fragment-major
    float* biasc         = (float*)(ws + 262144);                // 2 KB
    float* projP         = (float*)(ws + (1 << 20));             // 100000*8*4 = 3.2 MB

    prep_kernel <<<512, 256, 0, stream>>>(W_ih, W_hh, b_ih, b_hh, Wpk, biasc);
    lstm_kernel <<<GRID, 512, 0, stream>>>(inputs, hx, cx, Wpk, biasc, W_out, projP);
    match_kernel<<<(NUM_MATCHES + 255) / 256, 256, 0, stream>>>(matches, projP, b_out, out);
}

// Round 3
// 79.565 us; speedup vs baseline: 1.8918x; 1.8918x over previous
//
#include <hip/hip_runtime.h>
#include <hip/hip_bf16.h>

typedef __bf16 bf16x8 __attribute__((ext_vector_type(8)));
typedef float f32x4 __attribute__((ext_vector_type(4)));

#define NUM_TEAMS 100000
#define NUM_MATCHES 1000000
#define LOG2E 1.4426950408889634f
#define NWG 3126            // 1563 team-tiles x 2 hcol-halves
#define XQ 390              // NWG/8
#define XR 6                // NWG%8

__device__ __forceinline__ unsigned short f2bf(float x) {
    __hip_bfloat16 h = __float2bfloat16(x);
    return reinterpret_cast<unsigned short&>(h);
}
// single-instruction packed f32x2 -> bf16x2. No builtin on gfx950 (m240) -> asm.
__device__ __forceinline__ unsigned int cvtpk(float a, float b) {
    unsigned int r;
    asm("v_cvt_pk_bf16_f32 %0, %1, %2" : "=v"(r) : "v"(a), "v"(b));
    return r;
}
__device__ __forceinline__ float exp2_(float x) {
    float r; asm("v_exp_f32 %0, %1" : "=v"(r) : "v"(x)); return r;
}
__device__ __forceinline__ float rcp_(float x) {
    float r; asm("v_rcp_f32 %0, %1" : "=v"(r) : "v"(x)); return r;
}
// async global->LDS, 16B per lane. Dest = wave-uniform base + lane*16 (m104/m108).
__device__ __forceinline__ void load_lds16(const float* g, float* l) {
    __builtin_amdgcn_global_load_lds(
        (const __attribute__((address_space(1))) void*)g,
        (__attribute__((address_space(3))) void*)l, 16, 0, 0);
}

// ---------------- prep: pack W fragment-major bf16; biases pre-scaled by log2e ----------------
// Wpk u16 index = G*16384 + gate*4096 + ks*512 + l4*128 + l15*8 + e
//   holds W[row = gate*128 + G*16 + l15][k = ks*32 + l4*8 + e]  (W = [W_ih | W_hh])
__global__ __launch_bounds__(256) void prep_kernel(
    const float* __restrict__ W_ih, const float* __restrict__ W_hh,
    const float* __restrict__ b_ih, const float* __restrict__ b_hh,
    unsigned short* __restrict__ Wpk, float* __restrict__ biasc)
{
    int gid = blockIdx.x * 256 + threadIdx.x;   // 131072 bf16 elements
    int e = gid & 7;
    int chunk = gid >> 3;                        // 16B chunk id
    int l15 = chunk & 15;
    int l4 = (chunk >> 4) & 3;
    int rest = chunk >> 6;
    int ks = rest & 7;
    int gate = (rest >> 3) & 3;
    int G = rest >> 5;
    int row = gate * 128 + G * 16 + l15;
    int k = ks * 32 + l4 * 8 + e;
    float v = (k < 128) ? W_ih[row * 128 + k] : W_hh[row * 128 + (k - 128)];
    Wpk[gid] = f2bf(v);
    if (gid < 512) {
        float b = b_ih[gid] + b_hh[gid];
        float scale = ((gid >> 7) == 2) ? (2.0f * LOG2E) : (-LOG2E);
        biasc[gid] = b * scale;
    }
}

// ---------------- LSTM + fused partial proj ----------------
// Block: 256 thr = 4 waves. Tile: 64 teams x 64 hcols (hcol-half ch) x 4 gates.
// Round-0 skeleton (best measured) + two latency fixes:
//  (a) cx tile staged at kernel entry via 4 fire-and-forget global_load_lds_dwordx4
//      (16 KB LDS, zero VGPR/VALU) — removes the post-K-loop cx stall.
//  (b) A staging issues ALL 16 float4 loads back-to-back (256 B/thread in flight,
//      4x round-0's 4-pass window) before converting — LDS caps us at 3 blocks/CU
//      so the VGPR headroom (launch_bounds 3 -> ~170 regs/wave) is free.
// LDS 52.2 KB -> 3 blocks/CU x 4 waves = 12 waves/CU, independent barriers.
__global__ __launch_bounds__(256, 3) void lstm_kernel(
    const float* __restrict__ inputs, const float* __restrict__ hx,
    const float* __restrict__ cx, const unsigned short* __restrict__ Wpk,
    const float* __restrict__ biasc, const float* __restrict__ W_out,
    float* __restrict__ projP)
{
    __shared__ __align__(16) unsigned short Abf[64 * 256];  // 32 KB; reused as Hf f32[64][64]
    __shared__ __align__(16) float cxl[64 * 64];            // 16 KB cx tile
    __shared__ float Wlds[768];
    const int tid = threadIdx.x;

    // bijective chunked XCD swizzle: halves (2t,2t+1) land on the same XCD
    const int orig = blockIdx.x;
    const int xcd = orig & 7, idx = orig >> 3;
    const int wgid = (xcd < XR ? xcd * (XQ + 1) : XR * (XQ + 1) + (xcd - XR) * XQ) + idx;
    const int tile = wgid >> 1, ch = wgid & 1;
    const int brow = tile * 64;

    const int lane = tid & 63;
    const int w = tid >> 6;                          // wave 0..3
    const int l15 = lane & 15, l4 = lane >> 4;
    const int hl = w * 16 + l15;                     // hcol-local 0..63
    const int hcol = ch * 64 + hl;                   // global 0..127

    // ---- stage cx tile: 4 x global_load_lds_dwordx4, fire-and-forget ----
    // cxl[r][c] = cx[brow+r][ch*64+c]; instr p: wave w writes rows (p*4+w)*4 + l4
    {
        #pragma unroll
        for (int p = 0; p < 4; ++p) {
            int r = (p * 4 + w) * 4 + l4;
            int team = brow + r; if (team >= NUM_TEAMS) team = NUM_TEAMS - 1;
            load_lds16(cx + (size_t)team * 128 + ch * 64 + l15 * 4,
                       cxl + (p * 4 + w) * 256 + lane * 4);
        }
    }

    // ---- stage A = [inputs | hx] as bf16, XOR-swizzled: all 16 loads in flight ----
    {
        const int r0 = tid >> 4, seg = tid & 15;     // rows r0+16p, 16 segs of 16 k
        const float* srcb = (seg < 8) ? inputs + seg * 16 : hx + (seg - 8) * 16;
        float4 v[16];
        #pragma unroll
        for (int p = 0; p < 4; ++p) {
            int team = brow + p * 16 + r0; if (team >= NUM_TEAMS) team = NUM_TEAMS - 1;
            const float* src = srcb + (size_t)team * 128;
            v[p * 4 + 0] = *reinterpret_cast<const float4*>(src);
            v[p * 4 + 1] = *reinterpret_cast<const float4*>(src + 4);
            v[p * 4 + 2] = *reinterpret_cast<const float4*>(src + 8);
            v[p * 4 + 3] = *reinterpret_cast<const float4*>(src + 12);
        }
        char* lbw = reinterpret_cast<char*>(Abf);
        const int swz = (r0 & 7) << 4;               // (row&7) invariant under +16p
        #pragma unroll
        for (int p = 0; p < 4; ++p) {
            int base = (p * 16 + r0) * 512 + seg * 32;
            uint4 q0, q1;
            q0.x = cvtpk(v[p*4+0].x, v[p*4+0].y); q0.y = cvtpk(v[p*4+0].z, v[p*4+0].w);
            q0.z = cvtpk(v[p*4+1].x, v[p*4+1].y); q0.w = cvtpk(v[p*4+1].z, v[p*4+1].w);
            q1.x = cvtpk(v[p*4+2].x, v[p*4+2].y); q1.y = cvtpk(v[p*4+2].z, v[p*4+2].w);
            q1.z = cvtpk(v[p*4+3].x, v[p*4+3].y); q1.w = cvtpk(v[p*4+3].z, v[p*4+3].w);
            *reinterpret_cast<uint4*>(lbw + (base ^ swz)) = q0;
            *reinterpret_cast<uint4*>(lbw + ((base + 16) ^ swz)) = q1;
        }
        Wlds[tid] = W_out[tid];
        Wlds[256 + tid] = W_out[256 + tid];
        Wlds[512 + tid] = W_out[512 + tid];
    }

    // B fragment base: group G = ch*4 + w, contiguous 1KB per wave-load
    const unsigned short* bpg = Wpk + (size_t)(ch * 4 + w) * 16384 + lane * 8;
    const float bic = biasc[hcol];                   // -c*bi
    const float bfc = biasc[128 + hcol];             // -c*bf
    const float bgc = biasc[256 + hcol];             // +2c*bg
    const float boc = biasc[384 + hcol];             // -c*bo
    const int swzA = (l15 & 7) << 4;
    const int kf = l4 * 16;
    const char* pArow = reinterpret_cast<const char*>(Abf) + l15 * 512;

    f32x4 acc[4][4] = {};                            // [m][gate], 64 AGPRs

    __syncthreads();                                 // drains vmcnt too: cxl + Abf valid

    #pragma unroll
    for (int ks = 0; ks < 8; ++ks) {                 // K = 256 in steps of 32
        bf16x8 b0 = *(const bf16x8*)(bpg + ks * 512);
        bf16x8 b1 = *(const bf16x8*)(bpg + 4096 + ks * 512);
        bf16x8 b2 = *(const bf16x8*)(bpg + 8192 + ks * 512);
        bf16x8 b3 = *(const bf16x8*)(bpg + 12288 + ks * 512);
        const int ko = (ks * 64 + kf) ^ swzA;
        #pragma unroll
        for (int m = 0; m < 4; ++m) {
            bf16x8 af = *(const bf16x8*)(pArow + m * 8192 + ko);
            acc[m][0] = __builtin_amdgcn_mfma_f32_16x16x32_bf16(af, b0, acc[m][0], 0, 0, 0);
            acc[m][1] = __builtin_amdgcn_mfma_f32_16x16x32_bf16(af, b1, acc[m][1], 0, 0, 0);
            acc[m][2] = __builtin_amdgcn_mfma_f32_16x16x32_bf16(af, b2, acc[m][2], 0, 0, 0);
            acc[m][3] = __builtin_amdgcn_mfma_f32_16x16x32_bf16(af, b3, acc[m][3], 0, 0, 0);
        }
    }

    __syncthreads();                                 // all A reads done; LDS becomes Hf

    // ---- activations streamed per-m; h -> swizzled f32 [64][64] over Abf ----
    // C/D layout: col = l15 -> hcol, row = l4*4 + j -> team-local. cx from cxl.
    {
        char* lb = reinterpret_cast<char*>(Abf);
        #pragma unroll
        for (int m = 0; m < 4; ++m) {
            #pragma unroll
            for (int j = 0; j < 4; ++j) {
                float cxv = cxl[(m * 16 + l4 * 4 + j) * 64 + hl];
                float si = rcp_(1.0f + exp2_(fmaf(acc[m][0][j], -LOG2E, bic)));
                float sf = rcp_(1.0f + exp2_(fmaf(acc[m][1][j], -LOG2E, bfc)));
                float tg = fmaf(-2.0f, rcp_(1.0f + exp2_(fmaf(acc[m][2][j], 2.0f * LOG2E, bgc))), 1.0f);
                float so = rcp_(1.0f + exp2_(fmaf(acc[m][3][j], -LOG2E, boc)));
                float cn = fmaf(sf, cxv, si * tg);
                float tc = fmaf(-2.0f, rcp_(1.0f + exp2_(cn * (2.0f * LOG2E))), 1.0f);
                float hn = so * tc;
                int t = m * 16 + l4 * 4 + j;
                *reinterpret_cast<float*>(lb + ((t * 256 + hl * 4) ^ ((t & 7) << 4))) = hn;
            }
        }
    }
    __syncthreads();

    // ---- fused partial proj: 4 threads/team, 16 hcols each, 6 partial outputs ----
    {
        int tl = tid >> 2, sub = tid & 3;            // team-local 0..63, sub 0..3
        const char* lb = reinterpret_cast<const char*>(Abf);
        int hbase = tl * 256 + sub * 64;
        int hswz = (tl & 7) << 4;
        float a0 = 0.f, a1 = 0.f, a2 = 0.f, a3 = 0.f, a4 = 0.f, a5 = 0.f;
        #pragma unroll
        for (int c = 0; c < 4; ++c) {
            f32x4 h4 = *reinterpret_cast<const f32x4*>(lb + ((hbase + c * 16) ^ hswz));
            #pragma unroll
            for (int i = 0; i < 4; ++i) {
                float h = h4[i];
                int col = ch * 64 + sub * 16 + c * 4 + i;    // global hcol 0..127
                a0 += h * Wlds[col];       a1 += h * Wlds[256 + col]; a2 += h * Wlds[512 + col];
                a3 += h * Wlds[128 + col]; a4 += h * Wlds[384 + col]; a5 += h * Wlds[640 + col];
            }
        }
        a0 += __shfl_xor(a0, 1); a1 += __shfl_xor(a1, 1); a2 += __shfl_xor(a2, 1);
        a3 += __shfl_xor(a3, 1); a4 += __shfl_xor(a4, 1); a5 += __shfl_xor(a5, 1);
        a0 += __shfl_xor(a0, 2); a1 += __shfl_xor(a1, 2); a2 += __shfl_xor(a2, 2);
        a3 += __shfl_xor(a3, 2); a4 += __shfl_xor(a4, 2); a5 += __shfl_xor(a5, 2);
        int team = brow + tl;
        if (sub == 0 && team < NUM_TEAMS) {
            float4* o = reinterpret_cast<float4*>(projP + (size_t)team * 16 + ch * 8);
            o[0] = make_float4(a0, a1, a2, a2);      // home partial
            o[1] = make_float4(a3, a4, a5, a5);      // away partial
        }
    }
}

// ---------------- match head: sum half-partials; logits + b_out ; softmax ----------------
__global__ __launch_bounds__(256) void match_kernel(
    const int* __restrict__ matches, const float* __restrict__ projP,
    const float* __restrict__ b_out, float* __restrict__ out)
{
    int m = blockIdx.x * 256 + threadIdx.x;
    if (m >= NUM_MATCHES) return;
    int2 mi = reinterpret_cast<const int2*>(matches)[m];
    const float4* pp = reinterpret_cast<const float4*>(projP);
    float4 h0 = pp[(size_t)mi.x * 4 + 0];            // half0 home
    float4 h1 = pp[(size_t)mi.x * 4 + 2];            // half1 home
    float4 a0 = pp[(size_t)mi.y * 4 + 1];            // half0 away
    float4 a1 = pp[(size_t)mi.y * 4 + 3];            // half1 away
    float l0 = h0.x + h1.x + a0.x + a1.x + b_out[0];
    float l1 = h0.y + h1.y + a0.y + a1.y + b_out[1];
    float l2 = h0.z + h1.z + a0.z + a1.z + b_out[2];
    float mx = fmaxf(l0, fmaxf(l1, l2));
    float e0 = __expf(l0 - mx), e1 = __expf(l1 - mx), e2 = __expf(l2 - mx);
    float inv = 1.0f / (e0 + e1 + e2);
    out[3 * m + 0] = e0 * inv;
    out[3 * m + 1] = e1 * inv;
    out[3 * m + 2] = e2 * inv;
}

extern "C" void kernel_launch(void* const* d_in, const int* in_sizes, int n_in,
                              void* d_out, int out_size, void* d_ws, size_t ws_size,
                              hipStream_t stream) {
    const float* inputs = (const float*)d_in[0];
    const float* hx     = (const float*)d_in[1];
    const float* cx     = (const float*)d_in[2];
    const int*   matches= (const int*)d_in[3];
    const float* W_ih   = (const float*)d_in[4];
    const float* W_hh   = (const float*)d_in[5];
    const float* b_ih   = (const float*)d_in[6];
    const float* b_hh   = (const float*)d_in[7];
    const float* W_out  = (const float*)d_in[8];
    const float* b_out  = (const float*)d_in[9];
    float* out = (float*)d_out;

    char* ws = (char*)d_ws;
    unsigned short* Wpk  = (unsigned short*)ws;                  // 256 KB fragment-major
    float* biasc         = (float*)(ws + 262144);                // 2 KB
    float* projP         = (float*)(ws + (1 << 20));             // 100000*16*4 = 6.4 MB

    prep_kernel <<<512, 256, 0, stream>>>(W_ih, W_hh, b_ih, b_hh, Wpk, biasc);
    lstm_kernel <<<NWG, 256, 0, stream>>>(inputs, hx, cx, Wpk, biasc, W_out, projP);
    match_kernel<<<(NUM_MATCHES + 255) / 256, 256, 0, stream>>>(matches, projP, b_out, out);
}